// Round 6
// baseline (443.150 us; speedup 1.0000x reference)
//
#include <hip/hip_runtime.h>
#include <hip/hip_fp16.h>
#include <hip/hip_cooperative_groups.h>
#include <math.h>

namespace cg = cooperative_groups;

#define N_NODES 100000
#define N_EDGES 1600000
#define N_GRAPHS 64
#define NB 391        // buckets of 256 nodes: ceil(100000/256)
#define CAP 5504      // bucket slab capacity; E[bucket]=4096 -> huge margin

// ordered-uint encode for float atomicMax (monotone bijection)
__device__ __forceinline__ unsigned f2o(float f) {
    unsigned u = __float_as_uint(f);
    return (u & 0x80000000u) ? ~u : (u | 0x80000000u);
}
__device__ __forceinline__ float o2f(unsigned u) {
    return (u & 0x80000000u) ? __uint_as_float(u & 0x7fffffffu) : __uint_as_float(~u);
}

// 8B load of 4 fp16 -> float4
__device__ __forceinline__ float4 cvt8(float2 raw) {
    __half2 h0 = ((const __half2*)&raw)[0];
    __half2 h1 = ((const __half2*)&raw)[1];
    float2 f0 = __half22float2(h0);
    float2 f1 = __half22float2(h1);
    return make_float4(f0.x, f0.y, f1.x, f1.y);
}
__device__ __forceinline__ float4 loadh8(const __half* p) {
    return cvt8(*(const float2*)p);
}
__device__ __forceinline__ void storeh8(__half* p, float4 v) {
    __half2 o0 = __floats2half2_rn(v.x, v.y);
    __half2 o1 = __floats2half2_rn(v.z, v.w);
    float2 ow;
    ((__half2*)&ow)[0] = o0;
    ((__half2*)&ow)[1] = o1;
    *(float2*)p = ow;
}

typedef _Float16 h2r __attribute__((ext_vector_type(2)));
typedef _Float16 h4  __attribute__((ext_vector_type(4)));
union HB { float4 f4; h2r h[4]; };
union H4 { float2 f2; h4 h; };     // 8B = 4 packed fp16

// ================= prep: bucket -> gridsync -> csr -> gridsync -> gemm1 =================
// One cooperative kernel replaces 3 dispatches. LDS phases are unioned (max 43.5 KB).
struct PrepLDS {
    union {
        struct { int hist[NB]; int cur[NB]; } a;                                    // 3.1 KB
        struct { unsigned stage[CAP]; int c256[256]; int row256[256]; int cur256[256]; } b; // 25 KB
        struct { __half xsh[128][136]; __half wth[32][136]; } c;                    // 43.5 KB
    };
};

__global__ __launch_bounds__(256) void prep_kernel(const int* __restrict__ src, const int* __restrict__ dst,
                                                   const float* __restrict__ x, const float* __restrict__ W1,
                                                   int* __restrict__ bucketCursor, unsigned* __restrict__ ebuf,
                                                   int* __restrict__ colb, int* __restrict__ rowptr,
                                                   int* __restrict__ cnt, float* __restrict__ dis,
                                                   __half* __restrict__ hs1h) {
    __shared__ PrepLDS L;
    cg::grid_group grid = cg::this_grid();
    int tid = threadIdx.x;

    // ---- phase A: bucket edges by dst>>8 into fixed slabs (500 blocks x 3200 edges) ----
    {
        for (int b = tid; b < NB; b += 256) L.a.hist[b] = 0;
        __syncthreads();
        int e0 = blockIdx.x * 3200;
        for (int i = tid; i < 3200; i += 256) {
            int d = dst[e0 + i];
            atomicAdd(&L.a.hist[d >> 8], 1);
        }
        __syncthreads();
        for (int b = tid; b < NB; b += 256) {
            int h = L.a.hist[b];
            L.a.cur[b] = h ? atomicAdd(&bucketCursor[b], h) : 0;
        }
        __syncthreads();
        for (int i = tid; i < 3200; i += 256) {
            int d = dst[e0 + i];
            int s = src[e0 + i];
            int bu = d >> 8;
            int pos = atomicAdd(&L.a.cur[bu], 1);
            if (pos < CAP)
                ebuf[(size_t)bu * CAP + pos] = ((unsigned)(d & 255) << 24) | (unsigned)s;
        }
    }
    grid.sync();

    // ---- phase B: per-bucket CSR finalize (blocks 0..390) ----
    if (blockIdx.x < NB) {
        int b = blockIdx.x;
        int M = bucketCursor[b];
        if (M > CAP) M = CAP;
        L.b.c256[tid] = 0;
        __syncthreads();
        const unsigned* eb = ebuf + (size_t)b * CAP;
        for (int i = tid; i < M; i += 256) atomicAdd(&L.b.c256[eb[i] >> 24], 1);
        __syncthreads();
        if (tid < 64) {
            int c0 = L.b.c256[tid * 4], c1 = L.b.c256[tid * 4 + 1], c2 = L.b.c256[tid * 4 + 2], c3 = L.b.c256[tid * 4 + 3];
            int s = c0 + c1 + c2 + c3;
            int inc = s;
            #pragma unroll
            for (int o = 1; o < 64; o <<= 1) {
                int v = __shfl_up(inc, o, 64);
                if (tid >= o) inc += v;
            }
            int ex = inc - s;
            L.b.row256[tid * 4] = ex;
            L.b.row256[tid * 4 + 1] = ex + c0;
            L.b.row256[tid * 4 + 2] = ex + c0 + c1;
            L.b.row256[tid * 4 + 3] = ex + c0 + c1 + c2;
        }
        __syncthreads();
        L.b.cur256[tid] = L.b.row256[tid];
        int node = (b << 8) + tid;
        if (node < N_NODES) {
            int c = L.b.c256[tid];
            cnt[node] = c;
            dis[node] = rsqrtf((float)(c + 1));
            rowptr[node] = b * CAP + L.b.row256[tid];
        }
        __syncthreads();
        for (int i = tid; i < M; i += 256) {
            unsigned p = eb[i];
            int slot = atomicAdd(&L.b.cur256[p >> 24], 1);
            L.b.stage[slot] = p & 0xFFFFFFu;
        }
        __syncthreads();
        for (int i = tid; i < M; i += 256) colb[b * CAP + i] = (int)L.b.stage[i];
    }
    grid.sync();

    // ---- phase C: gemm1 (782 tiles of 128 rows over 500 blocks) ----
    for (int t = blockIdx.x; t < (N_NODES + 127) / 128; t += 500) {
        __syncthreads();
        int r0 = t * 128;
        for (int idx = tid; idx < 128 * 32; idx += 256) {
            int k = idx >> 5, j = idx & 31;
            L.c.wth[j][k] = __float2half_rn(W1[idx]);
        }
        for (int idx = tid; idx < 128 * 32; idx += 256) {
            int r = idx >> 5, c4 = idx & 31;
            int gr = r0 + r;
            float4 v = (gr < N_NODES) ? ((const float4*)x)[(size_t)gr * 32 + c4] : make_float4(0.f, 0.f, 0.f, 0.f);
            __half* p = &L.c.xsh[r][c4 * 4];
            *(__half2*)p       = __floats2half2_rn(v.x, v.y);
            *(__half2*)(p + 2) = __floats2half2_rn(v.z, v.w);
        }
        __syncthreads();
        int jg = tid & 7;
        int rg = tid >> 3;
        float acc[4][4];
        #pragma unroll
        for (int i = 0; i < 4; i++)
            #pragma unroll
            for (int j = 0; j < 4; j++) acc[i][j] = 0.f;
        for (int kc = 0; kc < 128; kc += 8) {
            HB xr[4], wr[4];
            #pragma unroll
            for (int ri = 0; ri < 4; ri++) xr[ri].f4 = *(const float4*)&L.c.xsh[rg + 32 * ri][kc];
            #pragma unroll
            for (int jj = 0; jj < 4; jj++) wr[jj].f4 = *(const float4*)&L.c.wth[jg * 4 + jj][kc];
            #pragma unroll
            for (int ri = 0; ri < 4; ri++) {
                #pragma unroll
                for (int jj = 0; jj < 4; jj++) {
                    #pragma unroll
                    for (int tt = 0; tt < 4; tt++) {
#if defined(__has_builtin) && __has_builtin(__builtin_amdgcn_fdot2)
                        acc[ri][jj] = __builtin_amdgcn_fdot2(xr[ri].h[tt], wr[jj].h[tt], acc[ri][jj], false);
#else
                        acc[ri][jj] += (float)xr[ri].h[tt][0] * (float)wr[jj].h[tt][0]
                                     + (float)xr[ri].h[tt][1] * (float)wr[jj].h[tt][1];
#endif
                    }
                }
            }
        }
        #pragma unroll
        for (int ri = 0; ri < 4; ri++) {
            int gr = r0 + rg + 32 * ri;
            if (gr < N_NODES) {
                float dr = dis[gr];
                float2 ow;
                ((__half2*)&ow)[0] = __floats2half2_rn(dr * acc[ri][0], dr * acc[ri][1]);
                ((__half2*)&ow)[1] = __floats2half2_rn(dr * acc[ri][2], dr * acc[ri][3]);
                *(float2*)&hs1h[(size_t)gr * 32 + jg * 4] = ow;
            }
        }
    }
}

// ---------------- agg1 (R2-proven): 2 rows per wave-iteration, 4 rows/wave,
//   2-deep pipeline, unified 64B rows (compulsory-per-XCD optimal). ----------------
__global__ __launch_bounds__(256) void agg1_kernel(const __half* __restrict__ hs1h, const int* __restrict__ colb,
                                                   const int* __restrict__ rowptr, const int* __restrict__ cnt,
                                                   const float* __restrict__ dis, const float* __restrict__ b1,
                                                   __half* __restrict__ t1h) {
    int tid = threadIdx.x;
    int wid = tid >> 6;
    int lane = tid & 63;
    int half = lane >> 5;        // row within iteration
    int es = (lane >> 3) & 3;    // edge slot 0..3
    int q = lane & 7;            // feature quad 0..7
    int w = blockIdx.x * 4 + wid;          // 25000 waves exactly
    int r0 = w * 4;

    H4 z; z.f2 = make_float2(0.f, 0.f);
    int r = r0 + half;
    int st = rowptr[r];
    int n = cnt[r];
    H4 pS = z, p0 = z, p1 = z, p2 = z, p3 = z, p4 = z, p5 = z;
    if (es == 0) pS.f2 = *(const float2*)(hs1h + (size_t)r * 32 + q * 4);
    {
        int e0 = es, e1 = 4 + es, e2 = 8 + es, e3 = 12 + es, e4 = 16 + es, e5 = 20 + es;
        if (e0 < n) p0.f2 = *(const float2*)(hs1h + (size_t)colb[st + e0] * 32 + q * 4);
        if (e1 < n) p1.f2 = *(const float2*)(hs1h + (size_t)colb[st + e1] * 32 + q * 4);
        if (e2 < n) p2.f2 = *(const float2*)(hs1h + (size_t)colb[st + e2] * 32 + q * 4);
        if (e3 < n) p3.f2 = *(const float2*)(hs1h + (size_t)colb[st + e3] * 32 + q * 4);
        if (e4 < n) p4.f2 = *(const float2*)(hs1h + (size_t)colb[st + e4] * 32 + q * 4);
        if (e5 < n) p5.f2 = *(const float2*)(hs1h + (size_t)colb[st + e5] * 32 + q * 4);
    }
    #pragma unroll
    for (int i = 0; i < 2; i++) {
        int rA = r;
        int stA = st, nA = n;
        H4 rS = pS, v0 = p0, v1 = p1, v2 = p2, v3 = p3, v4 = p4, v5 = p5;
        pS = z; p0 = z; p1 = z; p2 = z; p3 = z; p4 = z; p5 = z;
        if (i == 0) {
            r = r0 + 2 + half;
            st = rowptr[r];
            n = cnt[r];
            if (es == 0) pS.f2 = *(const float2*)(hs1h + (size_t)r * 32 + q * 4);
            int e0 = es, e1 = 4 + es, e2 = 8 + es, e3 = 12 + es, e4 = 16 + es, e5 = 20 + es;
            if (e0 < n) p0.f2 = *(const float2*)(hs1h + (size_t)colb[st + e0] * 32 + q * 4);
            if (e1 < n) p1.f2 = *(const float2*)(hs1h + (size_t)colb[st + e1] * 32 + q * 4);
            if (e2 < n) p2.f2 = *(const float2*)(hs1h + (size_t)colb[st + e2] * 32 + q * 4);
            if (e3 < n) p3.f2 = *(const float2*)(hs1h + (size_t)colb[st + e3] * 32 + q * 4);
            if (e4 < n) p4.f2 = *(const float2*)(hs1h + (size_t)colb[st + e4] * 32 + q * 4);
            if (e5 < n) p5.f2 = *(const float2*)(hs1h + (size_t)colb[st + e5] * 32 + q * 4);
        }
        h4 sh = (rS.h + (v0.h + v1.h)) + ((v2.h + v3.h) + (v4.h + v5.h));
        float4 a = make_float4((float)sh.x, (float)sh.y, (float)sh.z, (float)sh.w);
        for (int k = 24; k < nA; k += 8) {
            int e0 = k + es, e1 = k + 4 + es;
            if (e0 < nA) {
                float4 v = loadh8(hs1h + (size_t)colb[stA + e0] * 32 + q * 4);
                a.x += v.x; a.y += v.y; a.z += v.z; a.w += v.w;
            }
            if (e1 < nA) {
                float4 v = loadh8(hs1h + (size_t)colb[stA + e1] * 32 + q * 4);
                a.x += v.x; a.y += v.y; a.z += v.z; a.w += v.w;
            }
        }
        #pragma unroll
        for (int m = 8; m <= 16; m <<= 1) {
            a.x += __shfl_xor(a.x, m, 64);
            a.y += __shfl_xor(a.y, m, 64);
            a.z += __shfl_xor(a.z, m, 64);
            a.w += __shfl_xor(a.w, m, 64);
        }
        if (es == 0) {
            float4 bv = *(const float4*)&b1[q * 4];
            float dr = dis[rA];
            float4 v;
            v.x = dr * a.x + bv.x; v.y = dr * a.y + bv.y; v.z = dr * a.z + bv.z; v.w = dr * a.w + bv.w;
            v.x = v.x > 0.f ? v.x : 0.1f * v.x;
            v.y = v.y > 0.f ? v.y : 0.1f * v.y;
            v.z = v.z > 0.f ? v.z : 0.1f * v.z;
            v.w = v.w > 0.f ? v.w : 0.1f * v.w;
            v.x *= dr; v.y *= dr; v.z *= dr; v.w *= dr;
            storeh8(t1h + (size_t)rA * 32 + q * 4, v);
        }
    }
}

// ---------------- agg2 + gemm2 + pool + (last block) MLP head ----------------
struct A2L {
    union {
        struct { float as1[64][32]; float w2s[32][64]; float red[16][64]; } g;  // 20 KB
        struct { float A[64][64]; float B[64][128]; } m;                        // 48 KB
    };
};

__global__ __launch_bounds__(1024) void agg2gemm_kernel(const __half* __restrict__ t1h, const int* __restrict__ colb,
                                                        const int* __restrict__ rowptr, const int* __restrict__ cnt,
                                                        const float* __restrict__ dis,
                                                        const float* __restrict__ W2, const float* __restrict__ b2,
                                                        const int* __restrict__ batch, unsigned* __restrict__ gbufu,
                                                        unsigned* __restrict__ donecnt,
                                                        const float* __restrict__ Wl1, const float* __restrict__ bl1,
                                                        const float* __restrict__ Wl2, const float* __restrict__ bl2,
                                                        const float* __restrict__ Wl3, const float* __restrict__ bl3,
                                                        float* __restrict__ out) {
    __shared__ A2L L;
    __shared__ int finL;
    int tid = threadIdx.x;
    int r0 = blockIdx.x * 64;
    for (int idx = tid; idx < 32 * 64; idx += 1024) L.g.w2s[idx >> 6][idx & 63] = W2[idx];

    int wid = tid >> 6;          // wave 0..15
    int lane = tid & 63;
    int half = lane >> 5;
    int es = (lane >> 3) & 3;
    int q = lane & 7;
    int base = r0 + wid * 4;

    H4 z; z.f2 = make_float2(0.f, 0.f);
    int r = base + half;
    bool vld = r < N_NODES;
    int st = vld ? rowptr[r] : 0;
    int n  = vld ? cnt[r] : 0;
    H4 pS = z, p0 = z, p1 = z, p2 = z, p3 = z, p4 = z, p5 = z;
    if (vld && es == 0) pS.f2 = *(const float2*)(t1h + (size_t)r * 32 + q * 4);
    {
        int e0 = es, e1 = 4 + es, e2 = 8 + es, e3 = 12 + es, e4 = 16 + es, e5 = 20 + es;
        if (e0 < n) p0.f2 = *(const float2*)(t1h + (size_t)colb[st + e0] * 32 + q * 4);
        if (e1 < n) p1.f2 = *(const float2*)(t1h + (size_t)colb[st + e1] * 32 + q * 4);
        if (e2 < n) p2.f2 = *(const float2*)(t1h + (size_t)colb[st + e2] * 32 + q * 4);
        if (e3 < n) p3.f2 = *(const float2*)(t1h + (size_t)colb[st + e3] * 32 + q * 4);
        if (e4 < n) p4.f2 = *(const float2*)(t1h + (size_t)colb[st + e4] * 32 + q * 4);
        if (e5 < n) p5.f2 = *(const float2*)(t1h + (size_t)colb[st + e5] * 32 + q * 4);
    }
    #pragma unroll
    for (int i = 0; i < 2; i++) {
        int rA = i * 2;
        int rAg = base + rA + half;
        bool vA = rAg < N_NODES;
        int stA = st, nA = n;
        H4 rS = pS, v0 = p0, v1 = p1, v2 = p2, v3 = p3, v4 = p4, v5 = p5;
        pS = z; p0 = z; p1 = z; p2 = z; p3 = z; p4 = z; p5 = z;
        if (i == 0) {
            r = base + 2 + half;
            vld = r < N_NODES;
            st = vld ? rowptr[r] : 0;
            n  = vld ? cnt[r] : 0;
            if (vld && es == 0) pS.f2 = *(const float2*)(t1h + (size_t)r * 32 + q * 4);
            int e0 = es, e1 = 4 + es, e2 = 8 + es, e3 = 12 + es, e4 = 16 + es, e5 = 20 + es;
            if (e0 < n) p0.f2 = *(const float2*)(t1h + (size_t)colb[st + e0] * 32 + q * 4);
            if (e1 < n) p1.f2 = *(const float2*)(t1h + (size_t)colb[st + e1] * 32 + q * 4);
            if (e2 < n) p2.f2 = *(const float2*)(t1h + (size_t)colb[st + e2] * 32 + q * 4);
            if (e3 < n) p3.f2 = *(const float2*)(t1h + (size_t)colb[st + e3] * 32 + q * 4);
            if (e4 < n) p4.f2 = *(const float2*)(t1h + (size_t)colb[st + e4] * 32 + q * 4);
            if (e5 < n) p5.f2 = *(const float2*)(t1h + (size_t)colb[st + e5] * 32 + q * 4);
        }
        h4 sh = (rS.h + (v0.h + v1.h)) + ((v2.h + v3.h) + (v4.h + v5.h));
        float4 a = make_float4((float)sh.x, (float)sh.y, (float)sh.z, (float)sh.w);
        for (int k = 24; k < nA; k += 8) {
            int e0 = k + es, e1 = k + 4 + es;
            if (e0 < nA) {
                float4 v = loadh8(t1h + (size_t)colb[stA + e0] * 32 + q * 4);
                a.x += v.x; a.y += v.y; a.z += v.z; a.w += v.w;
            }
            if (e1 < nA) {
                float4 v = loadh8(t1h + (size_t)colb[stA + e1] * 32 + q * 4);
                a.x += v.x; a.y += v.y; a.z += v.z; a.w += v.w;
            }
        }
        #pragma unroll
        for (int m = 8; m <= 16; m <<= 1) {
            a.x += __shfl_xor(a.x, m, 64);
            a.y += __shfl_xor(a.y, m, 64);
            a.z += __shfl_xor(a.z, m, 64);
            a.w += __shfl_xor(a.w, m, 64);
        }
        if (es == 0 && vA) {
            float dr = dis[rAg];
            float4 o = make_float4(dr * a.x, dr * a.y, dr * a.z, dr * a.w);
            *(float4*)&L.g.as1[wid * 4 + rA + half][q * 4] = o;
        }
    }
    __syncthreads();

    // ---- gemm2 + max-pool ----
    int j = tid & 63;
    int rq = tid >> 6;
    float w2c[32];
    #pragma unroll
    for (int k = 0; k < 32; k++) w2c[k] = L.g.w2s[k][j];
    float bj = b2[j];
    int rend = (r0 + 64 <= N_NODES) ? 64 : (N_NODES - r0);
    int gfirst = batch[r0];
    int glast = batch[r0 + rend - 1];
    bool uni = (gfirst == glast);
    float runmax = -INFINITY;
    #pragma unroll
    for (int i = 0; i < 4; i++) {
        int rl = rq + i * 16;
        if (rl >= rend) break;
        float acc = bj;
        #pragma unroll
        for (int kc = 0; kc < 32; kc += 4) {
            float4 av = *(const float4*)&L.g.as1[rl][kc];
            acc += av.x * w2c[kc] + av.y * w2c[kc + 1] + av.z * w2c[kc + 2] + av.w * w2c[kc + 3];
        }
        if (uni) runmax = fmaxf(runmax, acc);
        else atomicMax(&gbufu[batch[r0 + rl] * 64 + j], f2o(acc));
    }
    if (uni) {
        L.g.red[rq][j] = runmax;
        __syncthreads();
        if (tid < 64) {
            float m = -INFINITY;
            #pragma unroll
            for (int k = 0; k < 16; k++) m = fmaxf(m, L.g.red[k][tid]);
            atomicMax(&gbufu[gfirst * 64 + tid], f2o(m));
        }
    }

    // ---- last-block-done MLP head (replaces mlp dispatch) ----
    __syncthreads();          // all this block's atomics issued & drained (barrier implies vmcnt(0))
    if (tid == 0) {
        __threadfence();
        unsigned p = atomicAdd(donecnt, 1u);
        finL = (p == gridDim.x - 1) ? 1 : 0;
    }
    __syncthreads();
    if (finL) {
        // re-read pooled maxima via returning atomics: bypasses possibly-stale
        // per-XCD L2 copies (no kernel-boundary flush anymore).
        for (int idx = tid; idx < 64 * 64; idx += 1024) {
            unsigned u = atomicMax(&gbufu[idx], 0u);
            L.m.A[idx >> 6][idx & 63] = o2f(u);
        }
        __syncthreads();
        {   // layer1: B[64][128] = lrelu(A @ Wl1 + bl1); chunked weights keep VGPR low
            int jj = tid & 127, rg = tid >> 7;
            float acc[8];
            #pragma unroll
            for (int i = 0; i < 8; i++) acc[i] = bl1[jj];
            for (int c = 0; c < 4; c++) {
                float wc[16];
                #pragma unroll
                for (int k = 0; k < 16; k++) wc[k] = Wl1[(c * 16 + k) * 128 + jj];
                #pragma unroll
                for (int i = 0; i < 8; i++) {
                    int rr = rg + 8 * i;
                    #pragma unroll
                    for (int k = 0; k < 16; k++) acc[i] += L.m.A[rr][c * 16 + k] * wc[k];
                }
            }
            #pragma unroll
            for (int i = 0; i < 8; i++) {
                float v = acc[i];
                L.m.B[rg + 8 * i][jj] = v > 0.f ? v : 0.1f * v;
            }
        }
        __syncthreads();
        {   // layer2: A[64][64] = lrelu(B @ Wl2 + bl2)
            int jj = tid & 63, rg = tid >> 6;
            float acc[4];
            #pragma unroll
            for (int i = 0; i < 4; i++) acc[i] = bl2[jj];
            for (int c = 0; c < 8; c++) {
                float wc[16];
                #pragma unroll
                for (int k = 0; k < 16; k++) wc[k] = Wl2[(c * 16 + k) * 64 + jj];
                #pragma unroll
                for (int i = 0; i < 4; i++) {
                    int rr = rg + 16 * i;
                    #pragma unroll
                    for (int k = 0; k < 16; k++) acc[i] += L.m.B[rr][c * 16 + k] * wc[k];
                }
            }
            __syncthreads();   // layer-1 reads of A fully done before overwrite? (they were; extra safety vs B-writers)
            #pragma unroll
            for (int i = 0; i < 4; i++) {
                float v = acc[i];
                L.m.A[rg + 16 * i][jj] = v > 0.f ? v : 0.1f * v;
            }
        }
        __syncthreads();
        if (tid < 64) {
            float acc = bl3[0];
            #pragma unroll
            for (int k = 0; k < 64; k++) acc += L.m.A[tid][k] * Wl3[k];
            out[tid] = acc;
        }
    }
}

extern "C" void kernel_launch(void* const* d_in, const int* in_sizes, int n_in,
                              void* d_out, int out_size, void* d_ws, size_t ws_size,
                              hipStream_t stream) {
    (void)in_sizes; (void)n_in; (void)out_size; (void)ws_size;
    const float* x    = (const float*)d_in[0];
    const int*   edge = (const int*)d_in[1];
    const int*   batch= (const int*)d_in[2];
    const float* W1   = (const float*)d_in[3];
    const float* b1   = (const float*)d_in[4];
    const float* W2   = (const float*)d_in[5];
    const float* b2   = (const float*)d_in[6];
    const float* Wl1  = (const float*)d_in[7];
    const float* bl1  = (const float*)d_in[8];
    const float* Wl2  = (const float*)d_in[9];
    const float* bl2  = (const float*)d_in[10];
    const float* Wl3  = (const float*)d_in[11];
    const float* bl3  = (const float*)d_in[12];
    const int* srcp = edge;
    const int* dstp = edge + N_EDGES;

    // workspace: zeroed region first = bucketCursor[NB] + gbufu[64*64] + donecnt[1]
    char* ws = (char*)d_ws;
    int*      bucketCursor = (int*)ws;
    unsigned* gbufu        = (unsigned*)(bucketCursor + NB);
    unsigned* donecnt      = gbufu + N_GRAPHS * 64;
    size_t zeroed = (size_t)(NB + N_GRAPHS * 64 + 1) * 4;
    size_t off = (zeroed + 255) & ~(size_t)255;
    auto alloc = [&](size_t bytes) { char* p = ws + off; off = (off + bytes + 255) & ~(size_t)255; return p; };
    float*    dis    = (float*)alloc((size_t)N_NODES * 4);
    int*      cnt    = (int*)alloc((size_t)N_NODES * 4);
    int*      rowptr = (int*)alloc((size_t)N_NODES * 4);
    unsigned* ebuf   = (unsigned*)alloc((size_t)NB * CAP * 4);
    int*      colb   = (int*)alloc((size_t)NB * CAP * 4);
    __half*   hs1h   = (__half*)alloc((size_t)N_NODES * 32 * 2);
    __half*   t1h    = (__half*)alloc((size_t)N_NODES * 32 * 2);

    hipMemsetAsync(ws, 0, zeroed, stream);

    void* pargs[] = { (void*)&srcp, (void*)&dstp, (void*)&x, (void*)&W1,
                      (void*)&bucketCursor, (void*)&ebuf, (void*)&colb,
                      (void*)&rowptr, (void*)&cnt, (void*)&dis, (void*)&hs1h };
    hipLaunchCooperativeKernel((void*)prep_kernel, dim3(500), dim3(256), pargs, 0, stream);

    agg1_kernel<<<6250, 256, 0, stream>>>(hs1h, colb, rowptr, cnt, dis, b1, t1h);

    agg2gemm_kernel<<<(N_NODES + 63) / 64, 1024, 0, stream>>>(t1h, colb, rowptr, cnt, dis, W2, b2, batch,
                                                              gbufu, donecnt, Wl1, bl1, Wl2, bl2, Wl3, bl3,
                                                              (float*)d_out);
}

// Round 7
// 283.201 us; speedup vs baseline: 1.5648x; 1.5648x over previous
//
#include <hip/hip_runtime.h>
#include <hip/hip_fp16.h>
#include <math.h>

#define N_NODES 100000
#define N_EDGES 1600000
#define N_GRAPHS 64
#define NB 391        // buckets of 256 nodes: ceil(100000/256)
#define CAP 5504      // bucket slab capacity; E[bucket]=4096 -> huge margin

// ordered-uint encode for float atomicMax (monotone bijection)
__device__ __forceinline__ unsigned f2o(float f) {
    unsigned u = __float_as_uint(f);
    return (u & 0x80000000u) ? ~u : (u | 0x80000000u);
}
__device__ __forceinline__ float o2f(unsigned u) {
    return (u & 0x80000000u) ? __uint_as_float(u & 0x7fffffffu) : __uint_as_float(~u);
}

// 8B load of 4 fp16 -> float4
__device__ __forceinline__ float4 cvt8(float2 raw) {
    __half2 h0 = ((const __half2*)&raw)[0];
    __half2 h1 = ((const __half2*)&raw)[1];
    float2 f0 = __half22float2(h0);
    float2 f1 = __half22float2(h1);
    return make_float4(f0.x, f0.y, f1.x, f1.y);
}
__device__ __forceinline__ float4 loadh8(const __half* p) {
    return cvt8(*(const float2*)p);
}
__device__ __forceinline__ void storeh8(__half* p, float4 v) {
    __half2 o0 = __floats2half2_rn(v.x, v.y);
    __half2 o1 = __floats2half2_rn(v.z, v.w);
    float2 ow;
    ((__half2*)&ow)[0] = o0;
    ((__half2*)&ow)[1] = o1;
    *(float2*)p = ow;
}

typedef _Float16 h2r __attribute__((ext_vector_type(2)));
typedef _Float16 h4  __attribute__((ext_vector_type(4)));
union HB { float4 f4; h2r h[4]; };
union H4 { float2 f2; h4 h; };     // 8B = 4 packed fp16

// ---------------- phase 1: bucket edges by dst>>8 into fixed slabs ----------------
__global__ __launch_bounds__(256) void bucket_kernel(const int* __restrict__ src, const int* __restrict__ dst,
                                                     int* __restrict__ bucketCursor, unsigned* __restrict__ ebuf) {
    __shared__ int hist[NB];
    __shared__ int cur[NB];
    int tid = threadIdx.x;
    for (int b = tid; b < NB; b += 256) hist[b] = 0;
    __syncthreads();
    int e0 = blockIdx.x * 3200;                    // 500 blocks x 3200 = 1.6M exactly
    for (int i = tid; i < 3200; i += 256) {
        int d = dst[e0 + i];
        atomicAdd(&hist[d >> 8], 1);
    }
    __syncthreads();
    for (int b = tid; b < NB; b += 256) {
        int h = hist[b];
        cur[b] = h ? atomicAdd(&bucketCursor[b], h) : 0;   // reserve contiguous range
    }
    __syncthreads();
    for (int i = tid; i < 3200; i += 256) {
        int d = dst[e0 + i];
        int s = src[e0 + i];
        int bu = d >> 8;
        int pos = atomicAdd(&cur[bu], 1);          // LDS cursor within reserved range
        if (pos < CAP)
            ebuf[(size_t)bu * CAP + pos] = ((unsigned)(d & 255) << 24) | (unsigned)s;
    }
}

// ---------------- phase 2: per-bucket CSR finalize, all in LDS ----------------
__global__ __launch_bounds__(256) void csr_kernel(const unsigned* __restrict__ ebuf,
                                                  const int* __restrict__ bucketCursor,
                                                  int* __restrict__ colb, int* __restrict__ rowptr,
                                                  int* __restrict__ cnt, float* __restrict__ dis) {
    __shared__ unsigned stage[CAP];
    __shared__ int c256[256], row256[256], cur256[256];
    int b = blockIdx.x;
    int tid = threadIdx.x;
    int M = bucketCursor[b];
    if (M > CAP) M = CAP;
    c256[tid] = 0;
    __syncthreads();
    const unsigned* eb = ebuf + (size_t)b * CAP;
    for (int i = tid; i < M; i += 256) atomicAdd(&c256[eb[i] >> 24], 1);
    __syncthreads();
    if (tid < 64) {                                 // wave 0: exclusive scan of 256 counters
        int c0 = c256[tid * 4], c1 = c256[tid * 4 + 1], c2 = c256[tid * 4 + 2], c3 = c256[tid * 4 + 3];
        int s = c0 + c1 + c2 + c3;
        int inc = s;
        #pragma unroll
        for (int o = 1; o < 64; o <<= 1) {
            int v = __shfl_up(inc, o, 64);
            if (tid >= o) inc += v;
        }
        int ex = inc - s;
        row256[tid * 4] = ex;
        row256[tid * 4 + 1] = ex + c0;
        row256[tid * 4 + 2] = ex + c0 + c1;
        row256[tid * 4 + 3] = ex + c0 + c1 + c2;
    }
    __syncthreads();
    cur256[tid] = row256[tid];
    int node = (b << 8) + tid;
    if (node < N_NODES) {
        int c = c256[tid];
        cnt[node] = c;
        dis[node] = rsqrtf((float)(c + 1));
        rowptr[node] = b * CAP + row256[tid];
    }
    __syncthreads();
    for (int i = tid; i < M; i += 256) {
        unsigned p = eb[i];
        int slot = atomicAdd(&cur256[p >> 24], 1);
        stage[slot] = p & 0xFFFFFFu;
    }
    __syncthreads();
    for (int i = tid; i < M; i += 256) colb[b * CAP + i] = (int)stage[i];
}

// ---------------- GEMM1: register-blocked 4x4, fp16 LDS operands, fp32 acc ----------------
__global__ __launch_bounds__(256) void gemm1_kernel(const float* __restrict__ x, const float* __restrict__ W1,
                                                    const float* __restrict__ dis, __half* __restrict__ hs1h) {
    __shared__ __half xsh[128][136];   // 34 KB
    __shared__ __half wth[32][136];    // 8.5 KB (W1^T)
    int tid = threadIdx.x;
    int r0 = blockIdx.x * 128;
    for (int idx = tid; idx < 128 * 32; idx += 256) {
        int k = idx >> 5, j = idx & 31;
        wth[j][k] = __float2half_rn(W1[idx]);
    }
    for (int idx = tid; idx < 128 * 32; idx += 256) {
        int r = idx >> 5, c4 = idx & 31;
        int gr = r0 + r;
        float4 v = (gr < N_NODES) ? ((const float4*)x)[(size_t)gr * 32 + c4] : make_float4(0.f, 0.f, 0.f, 0.f);
        __half* p = &xsh[r][c4 * 4];
        *(__half2*)p       = __floats2half2_rn(v.x, v.y);
        *(__half2*)(p + 2) = __floats2half2_rn(v.z, v.w);
    }
    __syncthreads();
    int jg = tid & 7;       // cols 4jg .. 4jg+3
    int rg = tid >> 3;      // rows rg + 32*ri
    float acc[4][4];
    #pragma unroll
    for (int i = 0; i < 4; i++)
        #pragma unroll
        for (int j = 0; j < 4; j++) acc[i][j] = 0.f;
    for (int kc = 0; kc < 128; kc += 8) {
        HB xr[4], wr[4];
        #pragma unroll
        for (int ri = 0; ri < 4; ri++) xr[ri].f4 = *(const float4*)&xsh[rg + 32 * ri][kc];
        #pragma unroll
        for (int jj = 0; jj < 4; jj++) wr[jj].f4 = *(const float4*)&wth[jg * 4 + jj][kc];
        #pragma unroll
        for (int ri = 0; ri < 4; ri++) {
            #pragma unroll
            for (int jj = 0; jj < 4; jj++) {
                #pragma unroll
                for (int t = 0; t < 4; t++) {
#if defined(__has_builtin) && __has_builtin(__builtin_amdgcn_fdot2)
                    acc[ri][jj] = __builtin_amdgcn_fdot2(xr[ri].h[t], wr[jj].h[t], acc[ri][jj], false);
#else
                    acc[ri][jj] += (float)xr[ri].h[t][0] * (float)wr[jj].h[t][0]
                                 + (float)xr[ri].h[t][1] * (float)wr[jj].h[t][1];
#endif
                }
            }
        }
    }
    #pragma unroll
    for (int ri = 0; ri < 4; ri++) {
        int gr = r0 + rg + 32 * ri;
        if (gr < N_NODES) {
            float dr = dis[gr];
            float2 ow;
            ((__half2*)&ow)[0] = __floats2half2_rn(dr * acc[ri][0], dr * acc[ri][1]);
            ((__half2*)&ow)[1] = __floats2half2_rn(dr * acc[ri][2], dr * acc[ri][3]);
            *(float2*)&hs1h[(size_t)gr * 32 + jg * 4] = ow;
        }
    }
}

// ---------------- agg1 (R2-proven): 2 rows per wave-iteration, 4 rows/wave,
//   2-deep pipeline, unified 64B rows (compulsory-per-XCD optimal). ----------------
__global__ __launch_bounds__(256) void agg1_kernel(const __half* __restrict__ hs1h, const int* __restrict__ colb,
                                                   const int* __restrict__ rowptr, const int* __restrict__ cnt,
                                                   const float* __restrict__ dis, const float* __restrict__ b1,
                                                   __half* __restrict__ t1h) {
    int tid = threadIdx.x;
    int wid = tid >> 6;
    int lane = tid & 63;
    int half = lane >> 5;        // row within iteration
    int es = (lane >> 3) & 3;    // edge slot 0..3
    int q = lane & 7;            // feature quad 0..7
    int w = blockIdx.x * 4 + wid;          // 25000 waves exactly
    int r0 = w * 4;

    H4 z; z.f2 = make_float2(0.f, 0.f);
    int r = r0 + half;
    int st = rowptr[r];
    int n = cnt[r];
    H4 pS = z, p0 = z, p1 = z, p2 = z, p3 = z, p4 = z, p5 = z;
    if (es == 0) pS.f2 = *(const float2*)(hs1h + (size_t)r * 32 + q * 4);
    {
        int e0 = es, e1 = 4 + es, e2 = 8 + es, e3 = 12 + es, e4 = 16 + es, e5 = 20 + es;
        if (e0 < n) p0.f2 = *(const float2*)(hs1h + (size_t)colb[st + e0] * 32 + q * 4);
        if (e1 < n) p1.f2 = *(const float2*)(hs1h + (size_t)colb[st + e1] * 32 + q * 4);
        if (e2 < n) p2.f2 = *(const float2*)(hs1h + (size_t)colb[st + e2] * 32 + q * 4);
        if (e3 < n) p3.f2 = *(const float2*)(hs1h + (size_t)colb[st + e3] * 32 + q * 4);
        if (e4 < n) p4.f2 = *(const float2*)(hs1h + (size_t)colb[st + e4] * 32 + q * 4);
        if (e5 < n) p5.f2 = *(const float2*)(hs1h + (size_t)colb[st + e5] * 32 + q * 4);
    }
    #pragma unroll
    for (int i = 0; i < 2; i++) {
        int rA = r;
        int stA = st, nA = n;
        H4 rS = pS, v0 = p0, v1 = p1, v2 = p2, v3 = p3, v4 = p4, v5 = p5;
        pS = z; p0 = z; p1 = z; p2 = z; p3 = z; p4 = z; p5 = z;
        if (i == 0) {
            r = r0 + 2 + half;
            st = rowptr[r];
            n = cnt[r];
            if (es == 0) pS.f2 = *(const float2*)(hs1h + (size_t)r * 32 + q * 4);
            int e0 = es, e1 = 4 + es, e2 = 8 + es, e3 = 12 + es, e4 = 16 + es, e5 = 20 + es;
            if (e0 < n) p0.f2 = *(const float2*)(hs1h + (size_t)colb[st + e0] * 32 + q * 4);
            if (e1 < n) p1.f2 = *(const float2*)(hs1h + (size_t)colb[st + e1] * 32 + q * 4);
            if (e2 < n) p2.f2 = *(const float2*)(hs1h + (size_t)colb[st + e2] * 32 + q * 4);
            if (e3 < n) p3.f2 = *(const float2*)(hs1h + (size_t)colb[st + e3] * 32 + q * 4);
            if (e4 < n) p4.f2 = *(const float2*)(hs1h + (size_t)colb[st + e4] * 32 + q * 4);
            if (e5 < n) p5.f2 = *(const float2*)(hs1h + (size_t)colb[st + e5] * 32 + q * 4);
        }
        h4 sh = (rS.h + (v0.h + v1.h)) + ((v2.h + v3.h) + (v4.h + v5.h));
        float4 a = make_float4((float)sh.x, (float)sh.y, (float)sh.z, (float)sh.w);
        for (int k = 24; k < nA; k += 8) {
            int e0 = k + es, e1 = k + 4 + es;
            if (e0 < nA) {
                float4 v = loadh8(hs1h + (size_t)colb[stA + e0] * 32 + q * 4);
                a.x += v.x; a.y += v.y; a.z += v.z; a.w += v.w;
            }
            if (e1 < nA) {
                float4 v = loadh8(hs1h + (size_t)colb[stA + e1] * 32 + q * 4);
                a.x += v.x; a.y += v.y; a.z += v.z; a.w += v.w;
            }
        }
        #pragma unroll
        for (int m = 8; m <= 16; m <<= 1) {
            a.x += __shfl_xor(a.x, m, 64);
            a.y += __shfl_xor(a.y, m, 64);
            a.z += __shfl_xor(a.z, m, 64);
            a.w += __shfl_xor(a.w, m, 64);
        }
        if (es == 0) {
            float4 bv = *(const float4*)&b1[q * 4];
            float dr = dis[rA];
            float4 v;
            v.x = dr * a.x + bv.x; v.y = dr * a.y + bv.y; v.z = dr * a.z + bv.z; v.w = dr * a.w + bv.w;
            v.x = v.x > 0.f ? v.x : 0.1f * v.x;
            v.y = v.y > 0.f ? v.y : 0.1f * v.y;
            v.z = v.z > 0.f ? v.z : 0.1f * v.z;
            v.w = v.w > 0.f ? v.w : 0.1f * v.w;
            v.x *= dr; v.y *= dr; v.z *= dr; v.w *= dr;
            storeh8(t1h + (size_t)rA * 32 + q * 4, v);
        }
    }
}

// ---------------- agg2 + gemm2 + pool + (last block) MLP head ----------------
// Agg/gemm identical to R2's verified 1024-thread kernel; MLP tail verified in R6.
struct A2L {
    union {
        struct { float as1[64][32]; float w2s[32][64]; float red[16][64]; } g;  // 20 KB
        struct { float A[64][64]; float B[64][128]; } m;                        // 48 KB
    };
};

__global__ __launch_bounds__(1024) void agg2gemm_kernel(const __half* __restrict__ t1h, const int* __restrict__ colb,
                                                        const int* __restrict__ rowptr, const int* __restrict__ cnt,
                                                        const float* __restrict__ dis,
                                                        const float* __restrict__ W2, const float* __restrict__ b2,
                                                        const int* __restrict__ batch, unsigned* __restrict__ gbufu,
                                                        unsigned* __restrict__ donecnt,
                                                        const float* __restrict__ Wl1, const float* __restrict__ bl1,
                                                        const float* __restrict__ Wl2, const float* __restrict__ bl2,
                                                        const float* __restrict__ Wl3, const float* __restrict__ bl3,
                                                        float* __restrict__ out) {
    __shared__ A2L L;
    __shared__ int finL;
    int tid = threadIdx.x;
    int r0 = blockIdx.x * 64;
    for (int idx = tid; idx < 32 * 64; idx += 1024) L.g.w2s[idx >> 6][idx & 63] = W2[idx];

    int wid = tid >> 6;          // wave 0..15
    int lane = tid & 63;
    int half = lane >> 5;
    int es = (lane >> 3) & 3;
    int q = lane & 7;
    int base = r0 + wid * 4;

    H4 z; z.f2 = make_float2(0.f, 0.f);
    int r = base + half;
    bool vld = r < N_NODES;
    int st = vld ? rowptr[r] : 0;
    int n  = vld ? cnt[r] : 0;
    H4 pS = z, p0 = z, p1 = z, p2 = z, p3 = z, p4 = z, p5 = z;
    if (vld && es == 0) pS.f2 = *(const float2*)(t1h + (size_t)r * 32 + q * 4);
    {
        int e0 = es, e1 = 4 + es, e2 = 8 + es, e3 = 12 + es, e4 = 16 + es, e5 = 20 + es;
        if (e0 < n) p0.f2 = *(const float2*)(t1h + (size_t)colb[st + e0] * 32 + q * 4);
        if (e1 < n) p1.f2 = *(const float2*)(t1h + (size_t)colb[st + e1] * 32 + q * 4);
        if (e2 < n) p2.f2 = *(const float2*)(t1h + (size_t)colb[st + e2] * 32 + q * 4);
        if (e3 < n) p3.f2 = *(const float2*)(t1h + (size_t)colb[st + e3] * 32 + q * 4);
        if (e4 < n) p4.f2 = *(const float2*)(t1h + (size_t)colb[st + e4] * 32 + q * 4);
        if (e5 < n) p5.f2 = *(const float2*)(t1h + (size_t)colb[st + e5] * 32 + q * 4);
    }
    #pragma unroll
    for (int i = 0; i < 2; i++) {
        int rA = i * 2;
        int rAg = base + rA + half;
        bool vA = rAg < N_NODES;
        int stA = st, nA = n;
        H4 rS = pS, v0 = p0, v1 = p1, v2 = p2, v3 = p3, v4 = p4, v5 = p5;
        pS = z; p0 = z; p1 = z; p2 = z; p3 = z; p4 = z; p5 = z;
        if (i == 0) {
            r = base + 2 + half;
            vld = r < N_NODES;
            st = vld ? rowptr[r] : 0;
            n  = vld ? cnt[r] : 0;
            if (vld && es == 0) pS.f2 = *(const float2*)(t1h + (size_t)r * 32 + q * 4);
            int e0 = es, e1 = 4 + es, e2 = 8 + es, e3 = 12 + es, e4 = 16 + es, e5 = 20 + es;
            if (e0 < n) p0.f2 = *(const float2*)(t1h + (size_t)colb[st + e0] * 32 + q * 4);
            if (e1 < n) p1.f2 = *(const float2*)(t1h + (size_t)colb[st + e1] * 32 + q * 4);
            if (e2 < n) p2.f2 = *(const float2*)(t1h + (size_t)colb[st + e2] * 32 + q * 4);
            if (e3 < n) p3.f2 = *(const float2*)(t1h + (size_t)colb[st + e3] * 32 + q * 4);
            if (e4 < n) p4.f2 = *(const float2*)(t1h + (size_t)colb[st + e4] * 32 + q * 4);
            if (e5 < n) p5.f2 = *(const float2*)(t1h + (size_t)colb[st + e5] * 32 + q * 4);
        }
        h4 sh = (rS.h + (v0.h + v1.h)) + ((v2.h + v3.h) + (v4.h + v5.h));
        float4 a = make_float4((float)sh.x, (float)sh.y, (float)sh.z, (float)sh.w);
        for (int k = 24; k < nA; k += 8) {
            int e0 = k + es, e1 = k + 4 + es;
            if (e0 < nA) {
                float4 v = loadh8(t1h + (size_t)colb[stA + e0] * 32 + q * 4);
                a.x += v.x; a.y += v.y; a.z += v.z; a.w += v.w;
            }
            if (e1 < nA) {
                float4 v = loadh8(t1h + (size_t)colb[stA + e1] * 32 + q * 4);
                a.x += v.x; a.y += v.y; a.z += v.z; a.w += v.w;
            }
        }
        #pragma unroll
        for (int m = 8; m <= 16; m <<= 1) {
            a.x += __shfl_xor(a.x, m, 64);
            a.y += __shfl_xor(a.y, m, 64);
            a.z += __shfl_xor(a.z, m, 64);
            a.w += __shfl_xor(a.w, m, 64);
        }
        if (es == 0 && vA) {
            float dr = dis[rAg];
            float4 o = make_float4(dr * a.x, dr * a.y, dr * a.z, dr * a.w);
            *(float4*)&L.g.as1[wid * 4 + rA + half][q * 4] = o;
        }
    }
    __syncthreads();

    // ---- gemm2 + max-pool ----
    int j = tid & 63;
    int rq = tid >> 6;
    float w2c[32];
    #pragma unroll
    for (int k = 0; k < 32; k++) w2c[k] = L.g.w2s[k][j];
    float bj = b2[j];
    int rend = (r0 + 64 <= N_NODES) ? 64 : (N_NODES - r0);
    int gfirst = batch[r0];
    int glast = batch[r0 + rend - 1];
    bool uni = (gfirst == glast);
    float runmax = -INFINITY;
    #pragma unroll
    for (int i = 0; i < 4; i++) {
        int rl = rq + i * 16;
        if (rl >= rend) break;
        float acc = bj;
        #pragma unroll
        for (int kc = 0; kc < 32; kc += 4) {
            float4 av = *(const float4*)&L.g.as1[rl][kc];
            acc += av.x * w2c[kc] + av.y * w2c[kc + 1] + av.z * w2c[kc + 2] + av.w * w2c[kc + 3];
        }
        if (uni) runmax = fmaxf(runmax, acc);
        else atomicMax(&gbufu[batch[r0 + rl] * 64 + j], f2o(acc));
    }
    if (uni) {
        L.g.red[rq][j] = runmax;
        __syncthreads();
        if (tid < 64) {
            float m = -INFINITY;
            #pragma unroll
            for (int k = 0; k < 16; k++) m = fmaxf(m, L.g.red[k][tid]);
            atomicMax(&gbufu[gfirst * 64 + tid], f2o(m));
        }
    }

    // ---- last-block-done MLP head (replaces mlp dispatch; verified R6) ----
    __syncthreads();
    if (tid == 0) {
        __threadfence();
        unsigned p = atomicAdd(donecnt, 1u);
        finL = (p == gridDim.x - 1) ? 1 : 0;
    }
    __syncthreads();
    if (finL) {
        // re-read pooled maxima via returning atomics (device-scope, bypasses stale L2)
        for (int idx = tid; idx < 64 * 64; idx += 1024) {
            unsigned u = atomicMax(&gbufu[idx], 0u);
            L.m.A[idx >> 6][idx & 63] = o2f(u);
        }
        __syncthreads();
        {   // layer1: B[64][128] = lrelu(A @ Wl1 + bl1)
            int jj = tid & 127, rg = tid >> 7;
            float acc[8];
            #pragma unroll
            for (int i = 0; i < 8; i++) acc[i] = bl1[jj];
            for (int c = 0; c < 4; c++) {
                float wc[16];
                #pragma unroll
                for (int k = 0; k < 16; k++) wc[k] = Wl1[(c * 16 + k) * 128 + jj];
                #pragma unroll
                for (int i = 0; i < 8; i++) {
                    int rr = rg + 8 * i;
                    #pragma unroll
                    for (int k = 0; k < 16; k++) acc[i] += L.m.A[rr][c * 16 + k] * wc[k];
                }
            }
            #pragma unroll
            for (int i = 0; i < 8; i++) {
                float v = acc[i];
                L.m.B[rg + 8 * i][jj] = v > 0.f ? v : 0.1f * v;
            }
        }
        __syncthreads();
        {   // layer2: A[64][64] = lrelu(B @ Wl2 + bl2)
            int jj = tid & 63, rg = tid >> 6;
            float acc[4];
            #pragma unroll
            for (int i = 0; i < 4; i++) acc[i] = bl2[jj];
            for (int c = 0; c < 8; c++) {
                float wc[16];
                #pragma unroll
                for (int k = 0; k < 16; k++) wc[k] = Wl2[(c * 16 + k) * 64 + jj];
                #pragma unroll
                for (int i = 0; i < 4; i++) {
                    int rr = rg + 16 * i;
                    #pragma unroll
                    for (int k = 0; k < 16; k++) acc[i] += L.m.B[rr][c * 16 + k] * wc[k];
                }
            }
            __syncthreads();
            #pragma unroll
            for (int i = 0; i < 4; i++) {
                float v = acc[i];
                L.m.A[rg + 16 * i][jj] = v > 0.f ? v : 0.1f * v;
            }
        }
        __syncthreads();
        if (tid < 64) {
            float acc = bl3[0];
            #pragma unroll
            for (int k = 0; k < 64; k++) acc += L.m.A[tid][k] * Wl3[k];
            out[tid] = acc;
        }
    }
}

extern "C" void kernel_launch(void* const* d_in, const int* in_sizes, int n_in,
                              void* d_out, int out_size, void* d_ws, size_t ws_size,
                              hipStream_t stream) {
    (void)in_sizes; (void)n_in; (void)out_size; (void)ws_size;
    const float* x    = (const float*)d_in[0];
    const int*   edge = (const int*)d_in[1];
    const int*   batch= (const int*)d_in[2];
    const float* W1   = (const float*)d_in[3];
    const float* b1   = (const float*)d_in[4];
    const float* W2   = (const float*)d_in[5];
    const float* b2   = (const float*)d_in[6];
    const float* Wl1  = (const float*)d_in[7];
    const float* bl1  = (const float*)d_in[8];
    const float* Wl2  = (const float*)d_in[9];
    const float* bl2  = (const float*)d_in[10];
    const float* Wl3  = (const float*)d_in[11];
    const float* bl3  = (const float*)d_in[12];
    const int* srcp = edge;
    const int* dstp = edge + N_EDGES;

    // workspace: zeroed region first = bucketCursor[NB] + gbufu[64*64] + donecnt[1]
    char* ws = (char*)d_ws;
    int*      bucketCursor = (int*)ws;
    unsigned* gbufu        = (unsigned*)(bucketCursor + NB);
    unsigned* donecnt      = gbufu + N_GRAPHS * 64;
    size_t zeroed = (size_t)(NB + N_GRAPHS * 64 + 1) * 4;
    size_t off = (zeroed + 255) & ~(size_t)255;
    auto alloc = [&](size_t bytes) { char* p = ws + off; off = (off + bytes + 255) & ~(size_t)255; return p; };
    float*    dis    = (float*)alloc((size_t)N_NODES * 4);
    int*      cnt    = (int*)alloc((size_t)N_NODES * 4);
    int*      rowptr = (int*)alloc((size_t)N_NODES * 4);
    unsigned* ebuf   = (unsigned*)alloc((size_t)NB * CAP * 4);   // bucketed packed edges, 8.6 MB
    int*      colb   = (int*)alloc((size_t)NB * CAP * 4);        // CSR columns (slab layout), 8.6 MB
    __half*   hs1h   = (__half*)alloc((size_t)N_NODES * 32 * 2);
    __half*   t1h    = (__half*)alloc((size_t)N_NODES * 32 * 2);

    hipMemsetAsync(ws, 0, zeroed, stream);

    bucket_kernel  <<<500, 256, 0, stream>>>(srcp, dstp, bucketCursor, ebuf);
    csr_kernel     <<<NB, 256, 0, stream>>>(ebuf, bucketCursor, colb, rowptr, cnt, dis);
    gemm1_kernel   <<<(N_NODES + 127) / 128, 256, 0, stream>>>(x, W1, dis, hs1h);
    agg1_kernel    <<<6250, 256, 0, stream>>>(hs1h, colb, rowptr, cnt, dis, b1, t1h);    // 25000 waves x 4 rows
    agg2gemm_kernel<<<(N_NODES + 63) / 64, 1024, 0, stream>>>(t1h, colb, rowptr, cnt, dis, W2, b2, batch,
                                                              gbufu, donecnt, Wl1, bl1, Wl2, bl2, Wl3, bl3,
                                                              (float*)d_out);
}

// Round 8
// 262.356 us; speedup vs baseline: 1.6891x; 1.0795x over previous
//
#include <hip/hip_runtime.h>
#include <hip/hip_fp16.h>
#include <math.h>

#define N_NODES 100000
#define N_EDGES 1600000
#define N_GRAPHS 64
#define NB 391        // buckets of 256 nodes: ceil(100000/256)
#define CAP 5504      // bucket slab capacity; E[bucket]=4096 -> huge margin

// ordered-uint encode for float atomicMax (monotone bijection)
__device__ __forceinline__ unsigned f2o(float f) {
    unsigned u = __float_as_uint(f);
    return (u & 0x80000000u) ? ~u : (u | 0x80000000u);
}
__device__ __forceinline__ float o2f(unsigned u) {
    return (u & 0x80000000u) ? __uint_as_float(u & 0x7fffffffu) : __uint_as_float(~u);
}

// 8B load of 4 fp16 -> float4
__device__ __forceinline__ float4 cvt8(float2 raw) {
    __half2 h0 = ((const __half2*)&raw)[0];
    __half2 h1 = ((const __half2*)&raw)[1];
    float2 f0 = __half22float2(h0);
    float2 f1 = __half22float2(h1);
    return make_float4(f0.x, f0.y, f1.x, f1.y);
}
__device__ __forceinline__ float4 loadh8(const __half* p) {
    return cvt8(*(const float2*)p);
}
__device__ __forceinline__ void storeh8(__half* p, float4 v) {
    __half2 o0 = __floats2half2_rn(v.x, v.y);
    __half2 o1 = __floats2half2_rn(v.z, v.w);
    float2 ow;
    ((__half2*)&ow)[0] = o0;
    ((__half2*)&ow)[1] = o1;
    *(float2*)p = ow;
}

typedef _Float16 h2r __attribute__((ext_vector_type(2)));
typedef _Float16 h4  __attribute__((ext_vector_type(4)));
union HB { float4 f4; h2r h[4]; };
union H4 { float2 f2; h4 h; };     // 8B = 4 packed fp16

// ---------------- phase 1: bucket edges by dst>>8 into fixed slabs.
//   v2: block-local counting sort so ebuf writes are contiguous per-bucket RUNS
//   (~6x fewer write-allocate lines than per-edge random 4B scatter). ----------------
__global__ __launch_bounds__(256) void bucket_kernel(const int* __restrict__ src, const int* __restrict__ dst,
                                                     int* __restrict__ bucketCursor, unsigned* __restrict__ ebuf) {
    __shared__ int hist[NB];
    __shared__ int lbase[NB];        // local exclusive scan of hist
    __shared__ int lcur[NB];         // local scatter cursor
    __shared__ int gbase[NB];        // global reserved base per bucket
    __shared__ unsigned lbuf[3200];  // bucket-sorted packed edges
    __shared__ unsigned short bkt[3200];
    int tid = threadIdx.x;
    for (int b = tid; b < NB; b += 256) hist[b] = 0;
    __syncthreads();
    int e0 = blockIdx.x * 3200;                    // 500 blocks x 3200 = 1.6M exactly
    for (int i = tid; i < 3200; i += 256) {
        int d = dst[e0 + i];
        atomicAdd(&hist[d >> 8], 1);
    }
    __syncthreads();
    // wave 0: exclusive scan of hist[391] in 64-lane chunks with carry
    if (tid < 64) {
        int carry = 0;
        #pragma unroll
        for (int c = 0; c < 7; c++) {                 // 7*64 = 448 >= 391
            int idx = c * 64 + tid;
            int v = (idx < NB) ? hist[idx] : 0;
            int inc = v;
            #pragma unroll
            for (int o = 1; o < 64; o <<= 1) {
                int t = __shfl_up(inc, o, 64);
                if (tid >= o) inc += t;
            }
            if (idx < NB) lbase[idx] = carry + inc - v;
            carry += __shfl(inc, 63, 64);
        }
    }
    __syncthreads();
    for (int b = tid; b < NB; b += 256) {
        int h = hist[b];
        gbase[b] = h ? atomicAdd(&bucketCursor[b], h) : 0;   // reserve contiguous global range
        lcur[b] = lbase[b];
    }
    __syncthreads();
    for (int i = tid; i < 3200; i += 256) {          // LDS counting-sort scatter
        int d = dst[e0 + i];
        int s = src[e0 + i];
        int bu = d >> 8;
        int lp = atomicAdd(&lcur[bu], 1);
        lbuf[lp] = ((unsigned)(d & 255) << 24) | (unsigned)s;
        bkt[lp] = (unsigned short)bu;
    }
    __syncthreads();
    for (int i = tid; i < 3200; i += 256) {          // coalesced-run global write
        int bu = bkt[i];
        int off = gbase[bu] + (i - lbase[bu]);       // rank within bucket
        if (off < CAP)
            ebuf[(size_t)bu * CAP + off] = lbuf[i];
    }
}

// ---------------- phase 2: per-bucket CSR finalize, all in LDS.
//   v2: ebuf staged to LDS on first read; scatter pass reads LDS (one global pass). ----------------
__global__ __launch_bounds__(256) void csr_kernel(const unsigned* __restrict__ ebuf,
                                                  const int* __restrict__ bucketCursor,
                                                  int* __restrict__ colb, int* __restrict__ rowptr,
                                                  int* __restrict__ cnt, float* __restrict__ dis) {
    __shared__ unsigned stage1[CAP];
    __shared__ unsigned stage2[CAP];
    __shared__ int c256[256], row256[256], cur256[256];
    int b = blockIdx.x;
    int tid = threadIdx.x;
    int M = bucketCursor[b];
    if (M > CAP) M = CAP;
    c256[tid] = 0;
    __syncthreads();
    const unsigned* eb = ebuf + (size_t)b * CAP;
    for (int i = tid; i < M; i += 256) {
        unsigned v = eb[i];
        stage1[i] = v;
        atomicAdd(&c256[v >> 24], 1);
    }
    __syncthreads();
    if (tid < 64) {                                 // wave 0: exclusive scan of 256 counters
        int c0 = c256[tid * 4], c1 = c256[tid * 4 + 1], c2 = c256[tid * 4 + 2], c3 = c256[tid * 4 + 3];
        int s = c0 + c1 + c2 + c3;
        int inc = s;
        #pragma unroll
        for (int o = 1; o < 64; o <<= 1) {
            int v = __shfl_up(inc, o, 64);
            if (tid >= o) inc += v;
        }
        int ex = inc - s;
        row256[tid * 4] = ex;
        row256[tid * 4 + 1] = ex + c0;
        row256[tid * 4 + 2] = ex + c0 + c1;
        row256[tid * 4 + 3] = ex + c0 + c1 + c2;
    }
    __syncthreads();
    cur256[tid] = row256[tid];
    int node = (b << 8) + tid;
    if (node < N_NODES) {
        int c = c256[tid];
        cnt[node] = c;
        dis[node] = rsqrtf((float)(c + 1));
        rowptr[node] = b * CAP + row256[tid];
    }
    __syncthreads();
    for (int i = tid; i < M; i += 256) {
        unsigned p = stage1[i];
        int slot = atomicAdd(&cur256[p >> 24], 1);
        stage2[slot] = p & 0xFFFFFFu;
    }
    __syncthreads();
    for (int i = tid; i < M; i += 256) colb[b * CAP + i] = (int)stage2[i];
}

// ---------------- GEMM1: register-blocked 4x4, fp16 LDS operands, fp32 acc ----------------
__global__ __launch_bounds__(256) void gemm1_kernel(const float* __restrict__ x, const float* __restrict__ W1,
                                                    const float* __restrict__ dis, __half* __restrict__ hs1h) {
    __shared__ __half xsh[128][136];   // 34 KB
    __shared__ __half wth[32][136];    // 8.5 KB (W1^T)
    int tid = threadIdx.x;
    int r0 = blockIdx.x * 128;
    for (int idx = tid; idx < 128 * 32; idx += 256) {
        int k = idx >> 5, j = idx & 31;
        wth[j][k] = __float2half_rn(W1[idx]);
    }
    for (int idx = tid; idx < 128 * 32; idx += 256) {
        int r = idx >> 5, c4 = idx & 31;
        int gr = r0 + r;
        float4 v = (gr < N_NODES) ? ((const float4*)x)[(size_t)gr * 32 + c4] : make_float4(0.f, 0.f, 0.f, 0.f);
        __half* p = &xsh[r][c4 * 4];
        *(__half2*)p       = __floats2half2_rn(v.x, v.y);
        *(__half2*)(p + 2) = __floats2half2_rn(v.z, v.w);
    }
    __syncthreads();
    int jg = tid & 7;       // cols 4jg .. 4jg+3
    int rg = tid >> 3;      // rows rg + 32*ri
    float acc[4][4];
    #pragma unroll
    for (int i = 0; i < 4; i++)
        #pragma unroll
        for (int j = 0; j < 4; j++) acc[i][j] = 0.f;
    for (int kc = 0; kc < 128; kc += 8) {
        HB xr[4], wr[4];
        #pragma unroll
        for (int ri = 0; ri < 4; ri++) xr[ri].f4 = *(const float4*)&xsh[rg + 32 * ri][kc];
        #pragma unroll
        for (int jj = 0; jj < 4; jj++) wr[jj].f4 = *(const float4*)&wth[jg * 4 + jj][kc];
        #pragma unroll
        for (int ri = 0; ri < 4; ri++) {
            #pragma unroll
            for (int jj = 0; jj < 4; jj++) {
                #pragma unroll
                for (int t = 0; t < 4; t++) {
#if defined(__has_builtin) && __has_builtin(__builtin_amdgcn_fdot2)
                    acc[ri][jj] = __builtin_amdgcn_fdot2(xr[ri].h[t], wr[jj].h[t], acc[ri][jj], false);
#else
                    acc[ri][jj] += (float)xr[ri].h[t][0] * (float)wr[jj].h[t][0]
                                 + (float)xr[ri].h[t][1] * (float)wr[jj].h[t][1];
#endif
                }
            }
        }
    }
    #pragma unroll
    for (int ri = 0; ri < 4; ri++) {
        int gr = r0 + rg + 32 * ri;
        if (gr < N_NODES) {
            float dr = dis[gr];
            float2 ow;
            ((__half2*)&ow)[0] = __floats2half2_rn(dr * acc[ri][0], dr * acc[ri][1]);
            ((__half2*)&ow)[1] = __floats2half2_rn(dr * acc[ri][2], dr * acc[ri][3]);
            *(float2*)&hs1h[(size_t)gr * 32 + jg * 4] = ow;
        }
    }
}

// ---------------- agg1 (R2-proven): 2 rows per wave-iteration, 4 rows/wave ----------------
__global__ __launch_bounds__(256) void agg1_kernel(const __half* __restrict__ hs1h, const int* __restrict__ colb,
                                                   const int* __restrict__ rowptr, const int* __restrict__ cnt,
                                                   const float* __restrict__ dis, const float* __restrict__ b1,
                                                   __half* __restrict__ t1h) {
    int tid = threadIdx.x;
    int wid = tid >> 6;
    int lane = tid & 63;
    int half = lane >> 5;        // row within iteration
    int es = (lane >> 3) & 3;    // edge slot 0..3
    int q = lane & 7;            // feature quad 0..7
    int w = blockIdx.x * 4 + wid;          // 25000 waves exactly
    int r0 = w * 4;

    H4 z; z.f2 = make_float2(0.f, 0.f);
    int r = r0 + half;
    int st = rowptr[r];
    int n = cnt[r];
    H4 pS = z, p0 = z, p1 = z, p2 = z, p3 = z, p4 = z, p5 = z;
    if (es == 0) pS.f2 = *(const float2*)(hs1h + (size_t)r * 32 + q * 4);
    {
        int e0 = es, e1 = 4 + es, e2 = 8 + es, e3 = 12 + es, e4 = 16 + es, e5 = 20 + es;
        if (e0 < n) p0.f2 = *(const float2*)(hs1h + (size_t)colb[st + e0] * 32 + q * 4);
        if (e1 < n) p1.f2 = *(const float2*)(hs1h + (size_t)colb[st + e1] * 32 + q * 4);
        if (e2 < n) p2.f2 = *(const float2*)(hs1h + (size_t)colb[st + e2] * 32 + q * 4);
        if (e3 < n) p3.f2 = *(const float2*)(hs1h + (size_t)colb[st + e3] * 32 + q * 4);
        if (e4 < n) p4.f2 = *(const float2*)(hs1h + (size_t)colb[st + e4] * 32 + q * 4);
        if (e5 < n) p5.f2 = *(const float2*)(hs1h + (size_t)colb[st + e5] * 32 + q * 4);
    }
    #pragma unroll
    for (int i = 0; i < 2; i++) {
        int rA = r;
        int stA = st, nA = n;
        H4 rS = pS, v0 = p0, v1 = p1, v2 = p2, v3 = p3, v4 = p4, v5 = p5;
        pS = z; p0 = z; p1 = z; p2 = z; p3 = z; p4 = z; p5 = z;
        if (i == 0) {
            r = r0 + 2 + half;
            st = rowptr[r];
            n = cnt[r];
            if (es == 0) pS.f2 = *(const float2*)(hs1h + (size_t)r * 32 + q * 4);
            int e0 = es, e1 = 4 + es, e2 = 8 + es, e3 = 12 + es, e4 = 16 + es, e5 = 20 + es;
            if (e0 < n) p0.f2 = *(const float2*)(hs1h + (size_t)colb[st + e0] * 32 + q * 4);
            if (e1 < n) p1.f2 = *(const float2*)(hs1h + (size_t)colb[st + e1] * 32 + q * 4);
            if (e2 < n) p2.f2 = *(const float2*)(hs1h + (size_t)colb[st + e2] * 32 + q * 4);
            if (e3 < n) p3.f2 = *(const float2*)(hs1h + (size_t)colb[st + e3] * 32 + q * 4);
            if (e4 < n) p4.f2 = *(const float2*)(hs1h + (size_t)colb[st + e4] * 32 + q * 4);
            if (e5 < n) p5.f2 = *(const float2*)(hs1h + (size_t)colb[st + e5] * 32 + q * 4);
        }
        h4 sh = (rS.h + (v0.h + v1.h)) + ((v2.h + v3.h) + (v4.h + v5.h));
        float4 a = make_float4((float)sh.x, (float)sh.y, (float)sh.z, (float)sh.w);
        for (int k = 24; k < nA; k += 8) {
            int e0 = k + es, e1 = k + 4 + es;
            if (e0 < nA) {
                float4 v = loadh8(hs1h + (size_t)colb[stA + e0] * 32 + q * 4);
                a.x += v.x; a.y += v.y; a.z += v.z; a.w += v.w;
            }
            if (e1 < nA) {
                float4 v = loadh8(hs1h + (size_t)colb[stA + e1] * 32 + q * 4);
                a.x += v.x; a.y += v.y; a.z += v.z; a.w += v.w;
            }
        }
        #pragma unroll
        for (int m = 8; m <= 16; m <<= 1) {
            a.x += __shfl_xor(a.x, m, 64);
            a.y += __shfl_xor(a.y, m, 64);
            a.z += __shfl_xor(a.z, m, 64);
            a.w += __shfl_xor(a.w, m, 64);
        }
        if (es == 0) {
            float4 bv = *(const float4*)&b1[q * 4];
            float dr = dis[rA];
            float4 v;
            v.x = dr * a.x + bv.x; v.y = dr * a.y + bv.y; v.z = dr * a.z + bv.z; v.w = dr * a.w + bv.w;
            v.x = v.x > 0.f ? v.x : 0.1f * v.x;
            v.y = v.y > 0.f ? v.y : 0.1f * v.y;
            v.z = v.z > 0.f ? v.z : 0.1f * v.z;
            v.w = v.w > 0.f ? v.w : 0.1f * v.w;
            v.x *= dr; v.y *= dr; v.z *= dr; v.w *= dr;
            storeh8(t1h + (size_t)rA * 32 + q * 4, v);
        }
    }
}

// ---------------- agg2+gemm2p (R2-exact): 1024 threads, 16 waves x 4 rows, 20.5 KB LDS ----------------
__global__ __launch_bounds__(1024) void agg2gemm_kernel(const __half* __restrict__ t1h, const int* __restrict__ colb,
                                                        const int* __restrict__ rowptr, const int* __restrict__ cnt,
                                                        const float* __restrict__ dis,
                                                        const float* __restrict__ W2, const float* __restrict__ b2,
                                                        const int* __restrict__ batch, unsigned* __restrict__ gbufu) {
    __shared__ float as1[64][32];    // 8 KB  (aggregated rows, fp32)
    __shared__ float w2s[32][64];    // 8 KB
    __shared__ float red[16][64];    // 4 KB
    int tid = threadIdx.x;
    int r0 = blockIdx.x * 64;
    for (int idx = tid; idx < 32 * 64; idx += 1024) w2s[idx >> 6][idx & 63] = W2[idx];

    int wid = tid >> 6;          // wave 0..15
    int lane = tid & 63;
    int half = lane >> 5;
    int es = (lane >> 3) & 3;
    int q = lane & 7;
    int base = r0 + wid * 4;

    H4 z; z.f2 = make_float2(0.f, 0.f);
    int r = base + half;
    bool vld = r < N_NODES;
    int st = vld ? rowptr[r] : 0;
    int n  = vld ? cnt[r] : 0;
    H4 pS = z, p0 = z, p1 = z, p2 = z, p3 = z, p4 = z, p5 = z;
    if (vld && es == 0) pS.f2 = *(const float2*)(t1h + (size_t)r * 32 + q * 4);
    {
        int e0 = es, e1 = 4 + es, e2 = 8 + es, e3 = 12 + es, e4 = 16 + es, e5 = 20 + es;
        if (e0 < n) p0.f2 = *(const float2*)(t1h + (size_t)colb[st + e0] * 32 + q * 4);
        if (e1 < n) p1.f2 = *(const float2*)(t1h + (size_t)colb[st + e1] * 32 + q * 4);
        if (e2 < n) p2.f2 = *(const float2*)(t1h + (size_t)colb[st + e2] * 32 + q * 4);
        if (e3 < n) p3.f2 = *(const float2*)(t1h + (size_t)colb[st + e3] * 32 + q * 4);
        if (e4 < n) p4.f2 = *(const float2*)(t1h + (size_t)colb[st + e4] * 32 + q * 4);
        if (e5 < n) p5.f2 = *(const float2*)(t1h + (size_t)colb[st + e5] * 32 + q * 4);
    }
    #pragma unroll
    for (int i = 0; i < 2; i++) {
        int rA = i * 2;
        int rAg = base + rA + half;
        bool vA = rAg < N_NODES;
        int stA = st, nA = n;
        H4 rS = pS, v0 = p0, v1 = p1, v2 = p2, v3 = p3, v4 = p4, v5 = p5;
        pS = z; p0 = z; p1 = z; p2 = z; p3 = z; p4 = z; p5 = z;
        if (i == 0) {
            r = base + 2 + half;
            vld = r < N_NODES;
            st = vld ? rowptr[r] : 0;
            n  = vld ? cnt[r] : 0;
            if (vld && es == 0) pS.f2 = *(const float2*)(t1h + (size_t)r * 32 + q * 4);
            int e0 = es, e1 = 4 + es, e2 = 8 + es, e3 = 12 + es, e4 = 16 + es, e5 = 20 + es;
            if (e0 < n) p0.f2 = *(const float2*)(t1h + (size_t)colb[st + e0] * 32 + q * 4);
            if (e1 < n) p1.f2 = *(const float2*)(t1h + (size_t)colb[st + e1] * 32 + q * 4);
            if (e2 < n) p2.f2 = *(const float2*)(t1h + (size_t)colb[st + e2] * 32 + q * 4);
            if (e3 < n) p3.f2 = *(const float2*)(t1h + (size_t)colb[st + e3] * 32 + q * 4);
            if (e4 < n) p4.f2 = *(const float2*)(t1h + (size_t)colb[st + e4] * 32 + q * 4);
            if (e5 < n) p5.f2 = *(const float2*)(t1h + (size_t)colb[st + e5] * 32 + q * 4);
        }
        h4 sh = (rS.h + (v0.h + v1.h)) + ((v2.h + v3.h) + (v4.h + v5.h));
        float4 a = make_float4((float)sh.x, (float)sh.y, (float)sh.z, (float)sh.w);
        for (int k = 24; k < nA; k += 8) {
            int e0 = k + es, e1 = k + 4 + es;
            if (e0 < nA) {
                float4 v = loadh8(t1h + (size_t)colb[stA + e0] * 32 + q * 4);
                a.x += v.x; a.y += v.y; a.z += v.z; a.w += v.w;
            }
            if (e1 < nA) {
                float4 v = loadh8(t1h + (size_t)colb[stA + e1] * 32 + q * 4);
                a.x += v.x; a.y += v.y; a.z += v.z; a.w += v.w;
            }
        }
        #pragma unroll
        for (int m = 8; m <= 16; m <<= 1) {
            a.x += __shfl_xor(a.x, m, 64);
            a.y += __shfl_xor(a.y, m, 64);
            a.z += __shfl_xor(a.z, m, 64);
            a.w += __shfl_xor(a.w, m, 64);
        }
        if (es == 0 && vA) {
            float dr = dis[rAg];
            float4 o = make_float4(dr * a.x, dr * a.y, dr * a.z, dr * a.w);
            *(float4*)&as1[wid * 4 + rA + half][q * 4] = o;
        }
    }
    __syncthreads();

    // ---- gemm2 + max-pool ----
    int j = tid & 63;
    int rq = tid >> 6;
    float w2c[32];
    #pragma unroll
    for (int k = 0; k < 32; k++) w2c[k] = w2s[k][j];
    float bj = b2[j];
    int rend = (r0 + 64 <= N_NODES) ? 64 : (N_NODES - r0);
    int gfirst = batch[r0];
    int glast = batch[r0 + rend - 1];
    bool uni = (gfirst == glast);
    float runmax = -INFINITY;
    #pragma unroll
    for (int i = 0; i < 4; i++) {
        int rl = rq + i * 16;
        if (rl >= rend) break;
        float acc = bj;
        #pragma unroll
        for (int kc = 0; kc < 32; kc += 4) {
            float4 av = *(const float4*)&as1[rl][kc];
            acc += av.x * w2c[kc] + av.y * w2c[kc + 1] + av.z * w2c[kc + 2] + av.w * w2c[kc + 3];
        }
        if (uni) runmax = fmaxf(runmax, acc);
        else atomicMax(&gbufu[batch[r0 + rl] * 64 + j], f2o(acc));
    }
    if (uni) {
        red[rq][j] = runmax;
        __syncthreads();
        if (tid < 64) {
            float m = -INFINITY;
            #pragma unroll
            for (int k = 0; k < 16; k++) m = fmaxf(m, red[k][tid]);
            atomicMax(&gbufu[gfirst * 64 + tid], f2o(m));
        }
    }
}

// ---------------- MLP head, single block (separate dispatch — 48 KB LDS is free here) ----------------
__global__ __launch_bounds__(256) void mlp_kernel(const unsigned* __restrict__ gbufu,
                                                  const float* __restrict__ Wl1, const float* __restrict__ bl1,
                                                  const float* __restrict__ Wl2, const float* __restrict__ bl2,
                                                  const float* __restrict__ Wl3, const float* __restrict__ bl3,
                                                  float* __restrict__ out) {
    __shared__ float A[64][64];
    __shared__ float B[64][128];
    int tid = threadIdx.x;
    for (int idx = tid; idx < 64 * 64; idx += 256) A[idx >> 6][idx & 63] = o2f(gbufu[idx]);
    __syncthreads();
    {
        int j = tid & 127;
        int rg = tid >> 7;
        float wc[64];
        #pragma unroll
        for (int k = 0; k < 64; k++) wc[k] = Wl1[k * 128 + j];
        float bj = bl1[j];
        for (int r = rg; r < 64; r += 2) {
            float acc = bj;
            #pragma unroll
            for (int kc = 0; kc < 64; kc += 4) {
                float4 av = *(const float4*)&A[r][kc];
                acc += av.x * wc[kc] + av.y * wc[kc + 1] + av.z * wc[kc + 2] + av.w * wc[kc + 3];
            }
            B[r][j] = acc > 0.f ? acc : 0.1f * acc;
        }
    }
    __syncthreads();
    {
        int j = tid & 63;
        int rg = tid >> 6;
        float wc[128];
        #pragma unroll
        for (int k = 0; k < 128; k++) wc[k] = Wl2[k * 64 + j];
        float bj = bl2[j];
        for (int r = rg; r < 64; r += 4) {
            float acc = bj;
            #pragma unroll
            for (int kc = 0; kc < 128; kc += 4) {
                float4 bv = *(const float4*)&B[r][kc];
                acc += bv.x * wc[kc] + bv.y * wc[kc + 1] + bv.z * wc[kc + 2] + bv.w * wc[kc + 3];
            }
            A[r][j] = acc > 0.f ? acc : 0.1f * acc;
        }
    }
    __syncthreads();
    if (tid < 64) {
        int r = tid;
        float acc = bl3[0];
        #pragma unroll
        for (int k = 0; k < 64; k++) acc += A[r][k] * Wl3[k];
        out[r] = acc;
    }
}

extern "C" void kernel_launch(void* const* d_in, const int* in_sizes, int n_in,
                              void* d_out, int out_size, void* d_ws, size_t ws_size,
                              hipStream_t stream) {
    (void)in_sizes; (void)n_in; (void)out_size; (void)ws_size;
    const float* x    = (const float*)d_in[0];
    const int*   edge = (const int*)d_in[1];
    const int*   batch= (const int*)d_in[2];
    const float* W1   = (const float*)d_in[3];
    const float* b1   = (const float*)d_in[4];
    const float* W2   = (const float*)d_in[5];
    const float* b2   = (const float*)d_in[6];
    const float* Wl1  = (const float*)d_in[7];
    const float* bl1  = (const float*)d_in[8];
    const float* Wl2  = (const float*)d_in[9];
    const float* bl2  = (const float*)d_in[10];
    const float* Wl3  = (const float*)d_in[11];
    const float* bl3  = (const float*)d_in[12];
    const int* srcp = edge;
    const int* dstp = edge + N_EDGES;

    // workspace layout: zeroed region first = bucketCursor[NB] + gbufu[64*64] -> one tiny memset
    char* ws = (char*)d_ws;
    int*      bucketCursor = (int*)ws;
    unsigned* gbufu        = (unsigned*)(bucketCursor + NB);
    size_t zeroed = (size_t)(NB + N_GRAPHS * 64) * 4;
    size_t off = (zeroed + 255) & ~(size_t)255;
    auto alloc = [&](size_t bytes) { char* p = ws + off; off = (off + bytes + 255) & ~(size_t)255; return p; };
    float*    dis    = (float*)alloc((size_t)N_NODES * 4);
    int*      cnt    = (int*)alloc((size_t)N_NODES * 4);
    int*      rowptr = (int*)alloc((size_t)N_NODES * 4);
    unsigned* ebuf   = (unsigned*)alloc((size_t)NB * CAP * 4);   // bucketed packed edges, 8.6 MB
    int*      colb   = (int*)alloc((size_t)NB * CAP * 4);        // CSR columns (slab layout), 8.6 MB
    __half*   hs1h   = (__half*)alloc((size_t)N_NODES * 32 * 2);
    __half*   t1h    = (__half*)alloc((size_t)N_NODES * 32 * 2);

    hipMemsetAsync(ws, 0, zeroed, stream);

    bucket_kernel  <<<500, 256, 0, stream>>>(srcp, dstp, bucketCursor, ebuf);
    csr_kernel     <<<NB, 256, 0, stream>>>(ebuf, bucketCursor, colb, rowptr, cnt, dis);
    gemm1_kernel   <<<(N_NODES + 127) / 128, 256, 0, stream>>>(x, W1, dis, hs1h);
    agg1_kernel    <<<6250, 256, 0, stream>>>(hs1h, colb, rowptr, cnt, dis, b1, t1h);    // 25000 waves x 4 rows
    agg2gemm_kernel<<<(N_NODES + 63) / 64, 1024, 0, stream>>>(t1h, colb, rowptr, cnt, dis, W2, b2, batch, gbufu);
    mlp_kernel     <<<1, 256, 0, stream>>>(gbufu, Wl1, bl1, Wl2, bl2, Wl3, bl3, (float*)d_out);
}